// Round 2
// 814.330 us; speedup vs baseline: 1.0752x; 1.0752x over previous
//
#include <hip/hip_runtime.h>
#include <cstdint>

typedef __bf16 bf16_t;
typedef __bf16 bf16x4 __attribute__((ext_vector_type(4)));
typedef __bf16 bf16x8 __attribute__((ext_vector_type(8)));
typedef float  f32x4  __attribute__((ext_vector_type(4)));
typedef float  f32x4u __attribute__((ext_vector_type(4), aligned(4)));  // 4B-aligned vector load

#define TOTAL_BINS 28749
#define WH_LD64    29312   // sum of round_up(L_i, 64)
#define N_HEADS    22
#define BATCH      2048
#define ROWS       4096    // BATCH * 2 channels
#define IDIM       2200
#define IDIM_P     2208    // K pad (mult of 32)
#define IDIM_NP    2304    // N pad (18 * 128 = 36 * 64)
#define H1DIM      1000
#define H1_NP      1024
#define H2DIM      50
#define ODIM       13
#define KSPLIT     8

__constant__ int d_LOC[23]  = {0,2490,4912,6895,8797,10612,12320,13913,15364,16748,
                               18086,19437,20770,21914,22984,24004,24907,25740,26544,
                               27130,27774,28241,28749};
// per-head offsets rounded up to 64 (packing layout for head_w bf16 copy)
__constant__ int d_HA64[23] = {0,2496,4928,6912,8832,10688,12416,14016,15488,16896,
                               18240,19648,20992,22144,23232,24256,25216,26112,26944,
                               27584,28288,28800,29312};

__device__ __forceinline__ void g2lds16(const void* g, void* l) {
  __builtin_amdgcn_global_load_lds((const __attribute__((address_space(1))) void*)g,
                                   (__attribute__((address_space(3))) void*)l, 16, 0, 0);
}

__device__ __forceinline__ f32x4 mfma16(bf16x8 a, bf16x8 b, f32x4 c) {
  return __builtin_amdgcn_mfma_f32_16x16x32_bf16(a, b, c, 0, 0, 0);
}

// ---------- weight conversion: fp32 (rows x cols) -> bf16 (prow x pcol), zero padded ----------
__global__ __launch_bounds__(256) void convert_pad(const float* __restrict__ src,
                                                   bf16_t* __restrict__ dst,
                                                   int rows, int cols, int prow, int pcol)
{
  size_t i = (size_t)blockIdx.x * 256 + threadIdx.x;
  size_t total = (size_t)prow * pcol;
  if (i >= total) return;
  int r = (int)(i / pcol);
  int c = (int)(i - (size_t)r * pcol);
  float v = (r < rows && c < cols) ? src[(size_t)r * cols + c] : 0.0f;
  dst[i] = (bf16_t)v;
}

// ---------- head_w repack: (50 x 28749) -> (64 x WH_LD64) bf16, per-head 64-aligned, zero pad ----
__global__ __launch_bounds__(256) void convert_headw(const float* __restrict__ src,
                                                     bf16_t* __restrict__ dst)
{
  size_t i = (size_t)blockIdx.x * 256 + threadIdx.x;
  if (i >= (size_t)64 * WH_LD64) return;
  int r = (int)(i / WH_LD64);
  int c = (int)(i - (size_t)r * WH_LD64);
  float v = 0.0f;
  #pragma unroll
  for (int h = 0; h < N_HEADS; h++) {
    int ha = d_HA64[h], hb = d_HA64[h + 1];
    if (c >= ha && c < hb) {
      int k = c - ha;
      int a = d_LOC[h];
      int L = d_LOC[h + 1] - a;
      if (r < 50 && k < L) v = src[(size_t)r * TOTAL_BINS + a + k];
    }
  }
  dst[i] = (bf16_t)v;
}

// ---------- stage 1: per-head GEMM, A direct-to-reg (prefetched, dwordx4), W LDS dbuf ----------
// grid (ROWS/64, 22); 256 thr = 4 waves; wave owns 16 rows x 64 cols; BK=64; 1 barrier/iter
__global__ __launch_bounds__(256) void head_gemm2(const float* __restrict__ X,
                                                  const bf16_t* __restrict__ Wh,
                                                  const float* __restrict__ headb,
                                                  bf16_t* __restrict__ Cmb)
{
  __shared__ __attribute__((aligned(16))) bf16_t Ws[2][64][72]; // +8 pad: bank-floor reads
  const int tid = threadIdx.x, lane = tid & 63, wid = tid >> 6;
  const int head = blockIdx.y;
  const int a   = d_LOC[head];
  const int ha  = d_HA64[head];
  const int L64 = d_HA64[head + 1] - ha;
  const int m0  = blockIdx.x * 64;
  const int la = lane & 15, lk = lane >> 4;
  const int wrow = m0 + wid * 16 + la;                 // A row this lane feeds
  const uint32_t rowbase = (uint32_t)wrow * TOTAL_BINS + (uint32_t)a;
  const uint32_t MAX4 = (uint32_t)ROWS * TOTAL_BINS - 4;

  // W staging: thread t -> Wh row n=t>>2, 16 bf16 at kgrp=(t&3)*16
  const int sn = tid >> 2, skg = (tid & 3) * 16;
  const bf16_t* wsrc = Wh + (size_t)sn * WH_LD64 + ha + skg;

  f32x4 acc[4] = {};

  // A fragment needs k = kq*32 + lk*8 + j  (two contiguous 32B chunks per lane)
  // -> 4 dwordx4 loads at float offsets {lk*8, lk*8+4, lk*8+32, lk*8+36}
  // tail overrun clamped to MAX4; garbage annihilated by zero-padded W rows.
  #define LOADA(dst, kbase) do {                                     \
    uint32_t b0_ = (kbase) + (uint32_t)(lk * 8);                     \
    dst[0] = *(const f32x4u*)(X + min(b0_,      MAX4));              \
    dst[1] = *(const f32x4u*)(X + min(b0_ + 4,  MAX4));              \
    dst[2] = *(const f32x4u*)(X + min(b0_ + 32, MAX4));              \
    dst[3] = *(const f32x4u*)(X + min(b0_ + 36, MAX4));              \
  } while (0)

  // prolog: W(0) -> Ws[0], prefetch A(0) to regs
  {
    uint4 w0 = *(const uint4*)(wsrc);
    uint4 w1 = *(const uint4*)(wsrc + 8);
    *(uint4*)(&Ws[0][sn][skg])     = w0;
    *(uint4*)(&Ws[0][sn][skg + 8]) = w1;
  }
  f32x4u ar[4];
  LOADA(ar, rowbase);

  const int nIter = L64 >> 6;
  for (int i = 0; i < nIter; i++) {
    __syncthreads();             // Ws[i&1] ready; prev g-loads drained
    const int cur = i & 1, nxt = cur ^ 1;
    uint4 nw0, nw1; f32x4u an[4];
    const bool more = (i + 1 < nIter);
    if (more) {                  // issue next-iter loads early (prefetch)
      const bf16_t* ws2 = wsrc + (size_t)(i + 1) * 64;
      nw0 = *(const uint4*)(ws2);
      nw1 = *(const uint4*)(ws2 + 8);
      LOADA(an, rowbase + (uint32_t)(i + 1) * 64);
    }
    // convert current A to frags: af[kq][j] = X[kb + kq*32 + lk*8 + j]
    bf16x8 af[2];
    #pragma unroll
    for (int kq = 0; kq < 2; kq++)
      #pragma unroll
      for (int j = 0; j < 8; j++)
        af[kq][j] = (bf16_t)ar[kq * 2 + (j >> 2)][j & 3];
    // B frags from LDS + MFMA
    #pragma unroll
    for (int kq = 0; kq < 2; kq++)
      #pragma unroll
      for (int j = 0; j < 4; j++) {
        bf16x8 bf = *(const bf16x8*)(&Ws[cur][j * 16 + la][kq * 32 + lk * 8]);
        acc[j] = mfma16(af[kq], bf, acc[j]);
      }
    if (more) {
      *(uint4*)(&Ws[nxt][sn][skg])     = nw0;
      *(uint4*)(&Ws[nxt][sn][skg + 8]) = nw1;
      #pragma unroll
      for (int q = 0; q < 4; q++) ar[q] = an[q];
    }
  }

  // epilogue: row = b*2+ch -> combined[b, head*100 + ch*50 + o]
  #pragma unroll
  for (int j = 0; j < 4; j++) {
    int o = j * 16 + la;
    if (o < 50) {
      float bv = headb[head * 50 + o];
      #pragma unroll
      for (int r = 0; r < 4; r++) {
        int gr = m0 + wid * 16 + lk * 4 + r;
        Cmb[(size_t)(gr >> 1) * IDIM_P + head * 100 + (gr & 1) * 50 + o] =
            (bf16_t)(acc[j][r] + bv);
      }
    }
  }
  #undef LOADA
}

// ---------- generic bf16 MFMA GEMM, 128x64 tile, double-buffered g2lds, 1 barrier/iter ----------
// C[m,n] = sum_k A[m,k] * W[n,k] + bias[n]; wave = 32 rows x 64 cols (splitk-proven layout), BK=32
__global__ __launch_bounds__(256) void gemm_bt64(const bf16_t* __restrict__ A, int lda,
                                                 const bf16_t* __restrict__ W, int ldb,
                                                 const float* __restrict__ bias,
                                                 void* __restrict__ Cout, int ldc,
                                                 int K, int N, int act, int out_f32)
{
  __shared__ __attribute__((aligned(16))) bf16_t As[2][128][32];
  __shared__ __attribute__((aligned(16))) bf16_t Bs[2][64][32];
  const int tid  = threadIdx.x;
  const int lane = tid & 63, wid = tid >> 6;
  const int m0 = blockIdx.x * 128;
  const int n0 = blockIdx.y * 64;
  const int la = lane & 15, lk = lane >> 4;
  const int wm = wid * 32;

  f32x4 acc[2][4] = {};

  const bf16_t* asrc0 = A + (size_t)(m0 + (tid >> 2)) * lda + (tid & 3) * 8;
  const bf16_t* asrc1 = asrc0 + (size_t)64 * lda;
  const bf16_t* wsrc  = W + (size_t)(n0 + (tid >> 2)) * ldb + (tid & 3) * 8;

  auto stage = [&](int buf, int k0) {
    g2lds16(asrc0 + k0, &As[buf][0][0] + tid * 8);
    g2lds16(asrc1 + k0, &As[buf][64][0] + tid * 8);
    g2lds16(wsrc  + k0, &Bs[buf][0][0] + tid * 8);
  };
  stage(0, 0);

  int i = 0;
  for (int k0 = 0; k0 < K; k0 += 32, i++) {
    __syncthreads();                       // drains vmcnt -> buf[i&1] ready
    const int cur = i & 1;
    if (k0 + 32 < K) stage(cur ^ 1, k0 + 32);
    bf16x8 af[2], bfr[4];
    #pragma unroll
    for (int ii = 0; ii < 2; ii++) af[ii]  = *(const bf16x8*)(&As[cur][wm + ii * 16 + la][lk * 8]);
    #pragma unroll
    for (int j = 0; j < 4; j++)    bfr[j] = *(const bf16x8*)(&Bs[cur][j * 16 + la][lk * 8]);
    #pragma unroll
    for (int ii = 0; ii < 2; ii++)
      #pragma unroll
      for (int j = 0; j < 4; j++)
        acc[ii][j] = mfma16(af[ii], bfr[j], acc[ii][j]);
  }

  float bv[4]; bool ok[4]; int gcv[4];
  #pragma unroll
  for (int j = 0; j < 4; j++) {
    int gc = n0 + j * 16 + la;
    gcv[j] = gc; ok[j] = gc < N;
    bv[j] = ok[j] ? bias[gc] : 0.0f;
  }
  #pragma unroll
  for (int ii = 0; ii < 2; ii++) {
    #pragma unroll
    for (int r = 0; r < 4; r++) {
      int gr = m0 + wm + ii * 16 + lk * 4 + r;
      #pragma unroll
      for (int j = 0; j < 4; j++) {
        if (ok[j]) {
          float v = acc[ii][j][r] + bv[j];
          if (act) v = fmaxf(v, 0.01f * v);
          if (out_f32) ((float*) Cout)[(size_t)gr * ldc + gcv[j]] = v;
          else         ((bf16_t*)Cout)[(size_t)gr * ldc + gcv[j]] = (bf16_t)v;
        }
      }
    }
  }
}

// ---------- stage 4 split-K: P[split][m][n] = sum_{k in chunk} h1[m,k]*w2[n,k] ----------
// grid (16, KSPLIT); 128x64 tile, wave = 32x64, BK=32, dbuf
__global__ __launch_bounds__(256) void gemm_splitk(const bf16_t* __restrict__ A,
                                                   const bf16_t* __restrict__ W,
                                                   float* __restrict__ P)
{
  __shared__ __attribute__((aligned(16))) bf16_t As[2][128][32];
  __shared__ __attribute__((aligned(16))) bf16_t Bs[2][64][32];
  const int tid  = threadIdx.x;
  const int lane = tid & 63, wid = tid >> 6;
  const int m0 = blockIdx.x * 128;
  const int split = blockIdx.y;
  const int kb = split * (H1_NP / KSPLIT);             // 128
  const int la = lane & 15, lk = lane >> 4;
  const int wm = wid * 32;

  f32x4 acc[2][4] = {};

  const bf16_t* asrc0 = A + (size_t)(m0 + (tid >> 2)) * H1_NP + kb + (tid & 3) * 8;
  const bf16_t* asrc1 = asrc0 + (size_t)64 * H1_NP;
  const bf16_t* wsrc  = W + (size_t)(tid >> 2) * H1_NP + kb + (tid & 3) * 8;

  auto stage = [&](int buf, int k0) {
    g2lds16(asrc0 + k0, &As[buf][0][0] + tid * 8);
    g2lds16(asrc1 + k0, &As[buf][64][0] + tid * 8);
    g2lds16(wsrc  + k0, &Bs[buf][0][0] + tid * 8);
  };
  stage(0, 0);

  #pragma unroll
  for (int i = 0; i < 4; i++) {                        // 4 * BK32 = 128
    __syncthreads();
    const int cur = i & 1;
    if (i < 3) stage(cur ^ 1, (i + 1) * 32);
    bf16x8 af[2], bfr[4];
    #pragma unroll
    for (int ii = 0; ii < 2; ii++) af[ii]  = *(const bf16x8*)(&As[cur][wm + ii * 16 + la][lk * 8]);
    #pragma unroll
    for (int j = 0; j < 4; j++)    bfr[j] = *(const bf16x8*)(&Bs[cur][j * 16 + la][lk * 8]);
    #pragma unroll
    for (int ii = 0; ii < 2; ii++)
      #pragma unroll
      for (int j = 0; j < 4; j++)
        acc[ii][j] = mfma16(af[ii], bfr[j], acc[ii][j]);
  }

  #pragma unroll
  for (int ii = 0; ii < 2; ii++)
    #pragma unroll
    for (int r = 0; r < 4; r++) {
      int gr = m0 + wm + ii * 16 + lk * 4 + r;
      #pragma unroll
      for (int j = 0; j < 4; j++)
        P[((size_t)split * BATCH + gr) * 64 + j * 16 + la] = acc[ii][j][r];
    }
}

// ---------- stage 5: sum splits + bias + lrelu, then 13-wide output GEMM (VALU) ----------
// grid (BATCH/16); block 256
__global__ __launch_bounds__(256) void finalize_tail(const float* __restrict__ P,
                                                     const float* __restrict__ b2,
                                                     const float* __restrict__ w3,
                                                     const float* __restrict__ b3,
                                                     float* __restrict__ out)
{
  __shared__ float h2s[16][64];
  const int r0 = blockIdx.x * 16;
  const int t = threadIdx.x;
  const int r = t >> 4, c4 = (t & 15) * 4;
  f32x4 s = {};
  #pragma unroll
  for (int sp = 0; sp < KSPLIT; sp++) {
    const f32x4 v = *(const f32x4*)(P + ((size_t)sp * BATCH + r0 + r) * 64 + c4);
    s.x += v.x; s.y += v.y; s.z += v.z; s.w += v.w;
  }
  #pragma unroll
  for (int c = 0; c < 4; c++) {
    int col = c4 + c;
    float v = s[c] + ((col < H2DIM) ? b2[col] : 0.0f);
    h2s[r][col] = fmaxf(v, 0.01f * v);
  }
  __syncthreads();
  if (t < 16 * ODIM) {
    int rr = t / ODIM, o = t - rr * ODIM;
    float acc = b3[o];
    #pragma unroll 10
    for (int k = 0; k < H2DIM; k++) acc += h2s[rr][k] * w3[o * H2DIM + k];
    out[(size_t)(r0 + rr) * ODIM + o] = acc;
  }
}

extern "C" void kernel_launch(void* const* d_in, const int* in_sizes, int n_in,
                              void* d_out, int out_size, void* d_ws, size_t ws_size,
                              hipStream_t stream)
{
  const float* X      = (const float*)d_in[0];
  const float* head_w = (const float*)d_in[1];
  const float* head_b = (const float*)d_in[2];
  const float* conc_w = (const float*)d_in[3];
  const float* conc_b = (const float*)d_in[4];
  const float* w1     = (const float*)d_in[5];
  const float* b1     = (const float*)d_in[6];
  const float* w2     = (const float*)d_in[7];
  const float* b2     = (const float*)d_in[8];
  const float* w3     = (const float*)d_in[9];
  const float* b3     = (const float*)d_in[10];

  char* p = (char*)d_ws;
  auto alloc = [&](size_t bytes) { char* r = p; p += (bytes + 255) & ~(size_t)255; return r; };
  bf16_t* headw_ws = (bf16_t*)alloc((size_t)64 * WH_LD64 * 2);     // 3.75 MB
  bf16_t* concw_ws = (bf16_t*)alloc((size_t)IDIM_NP * IDIM_P * 2); // 10.2 MB
  bf16_t* w1_ws    = (bf16_t*)alloc((size_t)H1_NP * IDIM_P * 2);   // 4.5 MB
  bf16_t* w2_ws    = (bf16_t*)alloc((size_t)128 * H1_NP * 2);      // 0.26 MB
  bf16_t* comb     = (bf16_t*)alloc((size_t)BATCH * IDIM_P * 2);   // 9.0 MB
  bf16_t* zbuf     = (bf16_t*)alloc((size_t)BATCH * IDIM_P * 2);   // 9.0 MB
  bf16_t* h1buf    = (bf16_t*)alloc((size_t)BATCH * H1_NP * 2);    // 4.2 MB
  float*  h2p      = (float*) alloc((size_t)KSPLIT * BATCH * 64 * 4); // 4.0 MB

  auto cgrid = [](size_t n) { return dim3((unsigned)((n + 255) / 256)); };

  convert_headw<<<cgrid((size_t)64 * WH_LD64), 256, 0, stream>>>(head_w, headw_ws);
  convert_pad<<<cgrid((size_t)IDIM_NP * IDIM_P), 256, 0, stream>>>(conc_w, concw_ws, IDIM, IDIM, IDIM_NP, IDIM_P);
  convert_pad<<<cgrid((size_t)H1_NP * IDIM_P), 256, 0, stream>>>(w1, w1_ws, H1DIM, IDIM, H1_NP, IDIM_P);
  convert_pad<<<cgrid((size_t)128 * H1_NP), 256, 0, stream>>>(w2, w2_ws, H2DIM, H1DIM, 128, H1_NP);

  head_gemm2<<<dim3(ROWS / 64, N_HEADS), 256, 0, stream>>>(X, headw_ws, head_b, comb);

  gemm_bt64<<<dim3(BATCH / 128, IDIM_NP / 64), 256, 0, stream>>>(
      comb, IDIM_P, concw_ws, IDIM_P, conc_b, zbuf, IDIM_P, IDIM_P, IDIM, 0, 0);
  gemm_bt64<<<dim3(BATCH / 128, H1_NP / 64), 256, 0, stream>>>(
      zbuf, IDIM_P, w1_ws, IDIM_P, b1, h1buf, H1_NP, IDIM_P, H1DIM, 1, 0);

  gemm_splitk<<<dim3(BATCH / 128, KSPLIT), 256, 0, stream>>>(h1buf, w2_ws, h2p);
  finalize_tail<<<dim3(BATCH / 16), 256, 0, stream>>>(h2p, b2, w3, b3, (float*)d_out);
}

// Round 3
// 801.699 us; speedup vs baseline: 1.0922x; 1.0158x over previous
//
#include <hip/hip_runtime.h>
#include <cstdint>

typedef __bf16 bf16_t;
typedef __bf16 bf16x4 __attribute__((ext_vector_type(4)));
typedef __bf16 bf16x8 __attribute__((ext_vector_type(8)));
typedef float  f32x4  __attribute__((ext_vector_type(4)));
typedef float  f32x4u __attribute__((ext_vector_type(4), aligned(4)));  // 4B-aligned vector load

#define TOTAL_BINS 28749
#define WH_LD64    29312   // sum of round_up(L_i, 64)
#define N_HEADS    22
#define BATCH      2048
#define ROWS       4096    // BATCH * 2 channels
#define IDIM       2200
#define IDIM_P     2208    // K pad (mult of 32)
#define IDIM_NP    2240    // N pad (35 * 64)
#define H1DIM      1000
#define H1_NP      1024
#define H2DIM      50
#define ODIM       13
#define KSPLIT     8

__constant__ int d_LOC[23]  = {0,2490,4912,6895,8797,10612,12320,13913,15364,16748,
                               18086,19437,20770,21914,22984,24004,24907,25740,26544,
                               27130,27774,28241,28749};
// per-head offsets rounded up to 64 (packing layout for head_w bf16 copy)
__constant__ int d_HA64[23] = {0,2496,4928,6912,8832,10688,12416,14016,15488,16896,
                               18240,19648,20992,22144,23232,24256,25216,26112,26944,
                               27584,28288,28800,29312};

__device__ __forceinline__ void g2lds16(const void* g, void* l) {
  __builtin_amdgcn_global_load_lds((const __attribute__((address_space(1))) void*)g,
                                   (__attribute__((address_space(3))) void*)l, 16, 0, 0);
}

__device__ __forceinline__ f32x4 mfma16(bf16x8 a, bf16x8 b, f32x4 c) {
  return __builtin_amdgcn_mfma_f32_16x16x32_bf16(a, b, c, 0, 0, 0);
}

// ---------- weight conversion: fp32 (rows x cols) -> bf16 (prow x pcol), zero padded ----------
// vectorized: 8 output elems / thread, b128 store (pcol always mult of 8)
__global__ __launch_bounds__(256) void convert_pad8(const float* __restrict__ src,
                                                    bf16_t* __restrict__ dst,
                                                    int rows, int cols, int prow, int pcol)
{
  size_t i = (size_t)blockIdx.x * 256 + threadIdx.x;
  int pc8 = pcol >> 3;
  if (i >= (size_t)prow * pc8) return;
  int r  = (int)(i / pc8);
  int c0 = (int)(i - (size_t)r * pc8) * 8;
  bf16x8 o;
  if (r < rows && c0 + 8 <= cols) {
    f32x4u a = *(const f32x4u*)(src + (size_t)r * cols + c0);
    f32x4u b = *(const f32x4u*)(src + (size_t)r * cols + c0 + 4);
    #pragma unroll
    for (int j = 0; j < 4; j++) { o[j] = (bf16_t)a[j]; o[4 + j] = (bf16_t)b[j]; }
  } else {
    #pragma unroll
    for (int j = 0; j < 8; j++) {
      int c = c0 + j;
      o[j] = (bf16_t)((r < rows && c < cols) ? src[(size_t)r * cols + c] : 0.0f);
    }
  }
  *(bf16x8*)(dst + (size_t)r * pcol + c0) = o;
}

// ---------- head_w repack: (50 x 28749) -> (64 x WH_LD64) bf16, per-head 64-aligned, zero pad ----
// 8 elems/thread; head boundaries are 64-aligned so an 8-pack never crosses heads
__global__ __launch_bounds__(256) void convert_headw8(const float* __restrict__ src,
                                                      bf16_t* __restrict__ dst)
{
  size_t i = (size_t)blockIdx.x * 256 + threadIdx.x;
  const int pc8 = WH_LD64 / 8;
  if (i >= (size_t)64 * pc8) return;
  int r  = (int)(i / pc8);
  int c0 = (int)(i - (size_t)r * pc8) * 8;
  int head = 0;
  #pragma unroll
  for (int h = 0; h < N_HEADS; h++) if (c0 >= d_HA64[h + 1]) head = h + 1;
  const int ha = d_HA64[head], a = d_LOC[head];
  const int L  = d_LOC[head + 1] - a;
  const int k0 = c0 - ha;
  bf16x8 o;
  if (r < 50 && k0 + 8 <= L) {
    const float* s = src + (size_t)r * TOTAL_BINS + a + k0;
    f32x4u x = *(const f32x4u*)(s);
    f32x4u y = *(const f32x4u*)(s + 4);
    #pragma unroll
    for (int j = 0; j < 4; j++) { o[j] = (bf16_t)x[j]; o[4 + j] = (bf16_t)y[j]; }
  } else {
    #pragma unroll
    for (int j = 0; j < 8; j++) {
      int k = k0 + j;
      o[j] = (bf16_t)((r < 50 && k < L) ? src[(size_t)r * TOTAL_BINS + a + k] : 0.0f);
    }
  }
  *(bf16x8*)(dst + (size_t)r * WH_LD64 + c0) = o;
}

// ---------- stage 1: per-head GEMM, A direct-to-reg (prefetched, dwordx4), W LDS dbuf ----------
// grid (ROWS/64, 22); 256 thr = 4 waves; wave owns 16 rows x 64 cols; BK=64; 1 barrier/iter
__global__ __launch_bounds__(256) void head_gemm2(const float* __restrict__ X,
                                                  const bf16_t* __restrict__ Wh,
                                                  const float* __restrict__ headb,
                                                  bf16_t* __restrict__ Cmb)
{
  __shared__ __attribute__((aligned(16))) bf16_t Ws[2][64][72]; // +8 pad: conflict-free phases
  const int tid = threadIdx.x, lane = tid & 63, wid = tid >> 6;
  const int head = blockIdx.y;
  const int a   = d_LOC[head];
  const int ha  = d_HA64[head];
  const int L64 = d_HA64[head + 1] - ha;
  const int m0  = blockIdx.x * 64;
  const int la = lane & 15, lk = lane >> 4;
  const int wrow = m0 + wid * 16 + la;                 // A row this lane feeds
  const uint32_t rowbase = (uint32_t)wrow * TOTAL_BINS + (uint32_t)a;
  const uint32_t MAX4 = (uint32_t)ROWS * TOTAL_BINS - 4;

  // W staging: thread t -> Wh row n=t>>2, 16 bf16 at kgrp=(t&3)*16
  const int sn = tid >> 2, skg = (tid & 3) * 16;
  const bf16_t* wsrc = Wh + (size_t)sn * WH_LD64 + ha + skg;

  f32x4 acc[4] = {};

  // A fragment needs k = kq*32 + lk*8 + j  (two contiguous 32B chunks per lane)
  // tail overrun clamped to MAX4; garbage annihilated by zero-padded W rows.
  #define LOADA(dst, kbase) do {                                     \
    uint32_t b0_ = (kbase) + (uint32_t)(lk * 8);                     \
    dst[0] = *(const f32x4u*)(X + min(b0_,      MAX4));              \
    dst[1] = *(const f32x4u*)(X + min(b0_ + 4,  MAX4));              \
    dst[2] = *(const f32x4u*)(X + min(b0_ + 32, MAX4));              \
    dst[3] = *(const f32x4u*)(X + min(b0_ + 36, MAX4));              \
  } while (0)

  // prolog: W(0) -> Ws[0], prefetch A(0) to regs
  {
    uint4 w0 = *(const uint4*)(wsrc);
    uint4 w1 = *(const uint4*)(wsrc + 8);
    *(uint4*)(&Ws[0][sn][skg])     = w0;
    *(uint4*)(&Ws[0][sn][skg + 8]) = w1;
  }
  f32x4u ar[4];
  LOADA(ar, rowbase);

  const int nIter = L64 >> 6;
  for (int i = 0; i < nIter; i++) {
    __syncthreads();             // Ws[i&1] ready
    const int cur = i & 1, nxt = cur ^ 1;
    uint4 nw0, nw1; f32x4u an[4];
    const bool more = (i + 1 < nIter);
    if (more) {                  // issue next-iter loads early (prefetch)
      const bf16_t* ws2 = wsrc + (size_t)(i + 1) * 64;
      nw0 = *(const uint4*)(ws2);
      nw1 = *(const uint4*)(ws2 + 8);
      LOADA(an, rowbase + (uint32_t)(i + 1) * 64);
    }
    // convert current A to frags: af[kq][j] = X[kb + kq*32 + lk*8 + j]
    bf16x8 af[2];
    #pragma unroll
    for (int kq = 0; kq < 2; kq++)
      #pragma unroll
      for (int j = 0; j < 8; j++)
        af[kq][j] = (bf16_t)ar[kq * 2 + (j >> 2)][j & 3];
    // B frags from LDS + MFMA
    #pragma unroll
    for (int kq = 0; kq < 2; kq++)
      #pragma unroll
      for (int j = 0; j < 4; j++) {
        bf16x8 bf = *(const bf16x8*)(&Ws[cur][j * 16 + la][kq * 32 + lk * 8]);
        acc[j] = mfma16(af[kq], bf, acc[j]);
      }
    if (more) {
      *(uint4*)(&Ws[nxt][sn][skg])     = nw0;
      *(uint4*)(&Ws[nxt][sn][skg + 8]) = nw1;
      #pragma unroll
      for (int q = 0; q < 4; q++) ar[q] = an[q];
    }
  }

  // epilogue: row = b*2+ch -> combined[b, head*100 + ch*50 + o]
  #pragma unroll
  for (int j = 0; j < 4; j++) {
    int o = j * 16 + la;
    if (o < 50) {
      float bv = headb[head * 50 + o];
      #pragma unroll
      for (int r = 0; r < 4; r++) {
        int gr = m0 + wid * 16 + lk * 4 + r;
        Cmb[(size_t)(gr >> 1) * IDIM_P + head * 100 + (gr & 1) * 50 + o] =
            (bf16_t)(acc[j][r] + bv);
      }
    }
  }
  #undef LOADA
}

// ---------- generic bf16 MFMA GEMM, 128x64 tile, dbuf g2lds, T2 XOR-swizzled LDS ----------
// C[m,n] = sum_k A[m,k] * W[n,k] + bias[n]; wave = 32 rows x 64 cols, BK=32
// swizzle (rule #21, both-sides): LDS dest linear; global SOURCE col-granule ^= (row>>1)&3;
// read col-granule ^= (la>>1)&3 -> b128 phases hit 8 distinct bank-quads (conflict-free)
__global__ __launch_bounds__(256) void gemm_bt64(const bf16_t* __restrict__ A, int lda,
                                                 const bf16_t* __restrict__ W, int ldb,
                                                 const float* __restrict__ bias,
                                                 void* __restrict__ Cout, int ldc,
                                                 int K, int N, int act, int out_f32)
{
  __shared__ __attribute__((aligned(16))) bf16_t As[2][128][32];
  __shared__ __attribute__((aligned(16))) bf16_t Bs[2][64][32];
  const int tid  = threadIdx.x;
  const int lane = tid & 63, wid = tid >> 6;
  const int m0 = blockIdx.x * 128;
  const int n0 = blockIdx.y * 64;
  const int la = lane & 15, lk = lane >> 4;
  const int wm = wid * 32;
  const int scg = (((tid & 3) ^ ((tid >> 3) & 3)) * 8);   // swizzled source col (elems)
  const int lks = ((lk ^ ((la >> 1) & 3)) * 8);           // swizzled read col (elems)

  f32x4 acc[2][4] = {};

  const bf16_t* asrc0 = A + (size_t)(m0 + (tid >> 2)) * lda + scg;
  const bf16_t* asrc1 = asrc0 + (size_t)64 * lda;
  const bf16_t* wsrc  = W + (size_t)(n0 + (tid >> 2)) * ldb + scg;

  auto stage = [&](int buf, int k0) {
    g2lds16(asrc0 + k0, &As[buf][0][0] + tid * 8);
    g2lds16(asrc1 + k0, &As[buf][64][0] + tid * 8);
    g2lds16(wsrc  + k0, &Bs[buf][0][0] + tid * 8);
  };
  stage(0, 0);

  int i = 0;
  for (int k0 = 0; k0 < K; k0 += 32, i++) {
    __syncthreads();                       // drains vmcnt -> buf[i&1] ready
    const int cur = i & 1;
    if (k0 + 32 < K) stage(cur ^ 1, k0 + 32);
    bf16x8 af[2], bfr[4];
    #pragma unroll
    for (int ii = 0; ii < 2; ii++) af[ii]  = *(const bf16x8*)(&As[cur][wm + ii * 16 + la][lks]);
    #pragma unroll
    for (int j = 0; j < 4; j++)    bfr[j] = *(const bf16x8*)(&Bs[cur][j * 16 + la][lks]);
    #pragma unroll
    for (int ii = 0; ii < 2; ii++)
      #pragma unroll
      for (int j = 0; j < 4; j++)
        acc[ii][j] = mfma16(af[ii], bfr[j], acc[ii][j]);
  }

  float bv[4]; bool ok[4]; int gcv[4];
  #pragma unroll
  for (int j = 0; j < 4; j++) {
    int gc = n0 + j * 16 + la;
    gcv[j] = gc; ok[j] = gc < N;
    bv[j] = ok[j] ? bias[gc] : 0.0f;
  }
  #pragma unroll
  for (int ii = 0; ii < 2; ii++) {
    #pragma unroll
    for (int r = 0; r < 4; r++) {
      int gr = m0 + wm + ii * 16 + lk * 4 + r;
      #pragma unroll
      for (int j = 0; j < 4; j++) {
        if (ok[j]) {
          float v = acc[ii][j][r] + bv[j];
          if (act) v = fmaxf(v, 0.01f * v);
          if (out_f32) ((float*) Cout)[(size_t)gr * ldc + gcv[j]] = v;
          else         ((bf16_t*)Cout)[(size_t)gr * ldc + gcv[j]] = (bf16_t)v;
        }
      }
    }
  }
}

// ---------- stage 4 split-K: P[split][m][n] = sum_{k in chunk} h1[m,k]*w2[n,k] ----------
// grid (16, KSPLIT); 128x64 tile, wave = 32x64, BK=32, dbuf, same T2 swizzle
__global__ __launch_bounds__(256) void gemm_splitk(const bf16_t* __restrict__ A,
                                                   const bf16_t* __restrict__ W,
                                                   float* __restrict__ P)
{
  __shared__ __attribute__((aligned(16))) bf16_t As[2][128][32];
  __shared__ __attribute__((aligned(16))) bf16_t Bs[2][64][32];
  const int tid  = threadIdx.x;
  const int lane = tid & 63, wid = tid >> 6;
  const int m0 = blockIdx.x * 128;
  const int split = blockIdx.y;
  const int kb = split * (H1_NP / KSPLIT);             // 128
  const int la = lane & 15, lk = lane >> 4;
  const int wm = wid * 32;
  const int scg = (((tid & 3) ^ ((tid >> 3) & 3)) * 8);
  const int lks = ((lk ^ ((la >> 1) & 3)) * 8);

  f32x4 acc[2][4] = {};

  const bf16_t* asrc0 = A + (size_t)(m0 + (tid >> 2)) * H1_NP + kb + scg;
  const bf16_t* asrc1 = asrc0 + (size_t)64 * H1_NP;
  const bf16_t* wsrc  = W + (size_t)(tid >> 2) * H1_NP + kb + scg;

  auto stage = [&](int buf, int k0) {
    g2lds16(asrc0 + k0, &As[buf][0][0] + tid * 8);
    g2lds16(asrc1 + k0, &As[buf][64][0] + tid * 8);
    g2lds16(wsrc  + k0, &Bs[buf][0][0] + tid * 8);
  };
  stage(0, 0);

  #pragma unroll
  for (int i = 0; i < 4; i++) {                        // 4 * BK32 = 128
    __syncthreads();
    const int cur = i & 1;
    if (i < 3) stage(cur ^ 1, (i + 1) * 32);
    bf16x8 af[2], bfr[4];
    #pragma unroll
    for (int ii = 0; ii < 2; ii++) af[ii]  = *(const bf16x8*)(&As[cur][wm + ii * 16 + la][lks]);
    #pragma unroll
    for (int j = 0; j < 4; j++)    bfr[j] = *(const bf16x8*)(&Bs[cur][j * 16 + la][lks]);
    #pragma unroll
    for (int ii = 0; ii < 2; ii++)
      #pragma unroll
      for (int j = 0; j < 4; j++)
        acc[ii][j] = mfma16(af[ii], bfr[j], acc[ii][j]);
  }

  #pragma unroll
  for (int ii = 0; ii < 2; ii++)
    #pragma unroll
    for (int r = 0; r < 4; r++) {
      int gr = m0 + wm + ii * 16 + lk * 4 + r;
      #pragma unroll
      for (int j = 0; j < 4; j++)
        P[((size_t)split * BATCH + gr) * 64 + j * 16 + la] = acc[ii][j][r];
    }
}

// ---------- stage 5: sum splits + bias + lrelu, then 13-wide output GEMM (VALU) ----------
// grid (BATCH/16); block 256
__global__ __launch_bounds__(256) void finalize_tail(const float* __restrict__ P,
                                                     const float* __restrict__ b2,
                                                     const float* __restrict__ w3,
                                                     const float* __restrict__ b3,
                                                     float* __restrict__ out)
{
  __shared__ float h2s[16][64];
  const int r0 = blockIdx.x * 16;
  const int t = threadIdx.x;
  const int r = t >> 4, c4 = (t & 15) * 4;
  f32x4 s = {};
  #pragma unroll
  for (int sp = 0; sp < KSPLIT; sp++) {
    const f32x4 v = *(const f32x4*)(P + ((size_t)sp * BATCH + r0 + r) * 64 + c4);
    s.x += v.x; s.y += v.y; s.z += v.z; s.w += v.w;
  }
  #pragma unroll
  for (int c = 0; c < 4; c++) {
    int col = c4 + c;
    float v = s[c] + ((col < H2DIM) ? b2[col] : 0.0f);
    h2s[r][col] = fmaxf(v, 0.01f * v);
  }
  __syncthreads();
  if (t < 16 * ODIM) {
    int rr = t / ODIM, o = t - rr * ODIM;
    float acc = b3[o];
    #pragma unroll 10
    for (int k = 0; k < H2DIM; k++) acc += h2s[rr][k] * w3[o * H2DIM + k];
    out[(size_t)(r0 + rr) * ODIM + o] = acc;
  }
}

extern "C" void kernel_launch(void* const* d_in, const int* in_sizes, int n_in,
                              void* d_out, int out_size, void* d_ws, size_t ws_size,
                              hipStream_t stream)
{
  const float* X      = (const float*)d_in[0];
  const float* head_w = (const float*)d_in[1];
  const float* head_b = (const float*)d_in[2];
  const float* conc_w = (const float*)d_in[3];
  const float* conc_b = (const float*)d_in[4];
  const float* w1     = (const float*)d_in[5];
  const float* b1     = (const float*)d_in[6];
  const float* w2     = (const float*)d_in[7];
  const float* b2     = (const float*)d_in[8];
  const float* w3     = (const float*)d_in[9];
  const float* b3     = (const float*)d_in[10];

  char* p = (char*)d_ws;
  auto alloc = [&](size_t bytes) { char* r = p; p += (bytes + 255) & ~(size_t)255; return r; };
  bf16_t* headw_ws = (bf16_t*)alloc((size_t)64 * WH_LD64 * 2);     // 3.75 MB
  bf16_t* concw_ws = (bf16_t*)alloc((size_t)IDIM_NP * IDIM_P * 2); // 9.9 MB
  bf16_t* w1_ws    = (bf16_t*)alloc((size_t)H1_NP * IDIM_P * 2);   // 4.5 MB
  bf16_t* w2_ws    = (bf16_t*)alloc((size_t)128 * H1_NP * 2);      // 0.26 MB
  bf16_t* comb     = (bf16_t*)alloc((size_t)BATCH * IDIM_P * 2);   // 9.0 MB
  bf16_t* zbuf     = (bf16_t*)alloc((size_t)BATCH * IDIM_P * 2);   // 9.0 MB
  bf16_t* h1buf    = (bf16_t*)alloc((size_t)BATCH * H1_NP * 2);    // 4.2 MB
  float*  h2p      = (float*) alloc((size_t)KSPLIT * BATCH * 64 * 4); // 4.0 MB

  auto cgrid = [](size_t n) { return dim3((unsigned)((n + 255) / 256)); };

  convert_headw8<<<cgrid((size_t)64 * WH_LD64 / 8), 256, 0, stream>>>(head_w, headw_ws);
  convert_pad8<<<cgrid((size_t)IDIM_NP * IDIM_P / 8), 256, 0, stream>>>(conc_w, concw_ws, IDIM, IDIM, IDIM_NP, IDIM_P);
  convert_pad8<<<cgrid((size_t)H1_NP * IDIM_P / 8), 256, 0, stream>>>(w1, w1_ws, H1DIM, IDIM, H1_NP, IDIM_P);
  convert_pad8<<<cgrid((size_t)128 * H1_NP / 8), 256, 0, stream>>>(w2, w2_ws, H2DIM, H1DIM, 128, H1_NP);

  head_gemm2<<<dim3(ROWS / 64, N_HEADS), 256, 0, stream>>>(X, headw_ws, head_b, comb);

  gemm_bt64<<<dim3(BATCH / 128, IDIM_NP / 64), 256, 0, stream>>>(
      comb, IDIM_P, concw_ws, IDIM_P, conc_b, zbuf, IDIM_P, IDIM_P, IDIM, 0, 0);
  gemm_bt64<<<dim3(BATCH / 128, H1_NP / 64), 256, 0, stream>>>(
      zbuf, IDIM_P, w1_ws, IDIM_P, b1, h1buf, H1_NP, IDIM_P, H1DIM, 1, 0);

  gemm_splitk<<<dim3(BATCH / 128, KSPLIT), 256, 0, stream>>>(h1buf, w2_ws, h2p);
  finalize_tail<<<dim3(BATCH / 16), 256, 0, stream>>>(h2p, b2, w3, b3, (float*)d_out);
}

// Round 4
// 771.681 us; speedup vs baseline: 1.1347x; 1.0389x over previous
//
#include <hip/hip_runtime.h>
#include <cstdint>

typedef __bf16 bf16_t;
typedef __bf16 bf16x4 __attribute__((ext_vector_type(4)));
typedef __bf16 bf16x8 __attribute__((ext_vector_type(8)));
typedef float  f32x4  __attribute__((ext_vector_type(4)));
typedef float  f32x4u __attribute__((ext_vector_type(4), aligned(4)));  // 4B-aligned vector load

#define TOTAL_BINS 28749
#define WH_LD64    29312   // sum of round_up(L_i, 64)
#define N_HEADS    22
#define BATCH      2048
#define ROWS       4096    // BATCH * 2 channels
#define IDIM       2200
#define IDIM_P     2208    // K pad (mult of 32)
#define IDIM_NP    2240    // N pad (35 * 64)
#define H1DIM      1000
#define H1_NP      1024
#define H2DIM      50
#define ODIM       13
#define KSPLIT     8
#define KCH_W1     1120    // w1 split-K chunk (mult of 32; 2208 = 1120 + 1088)

// fused-convert block partition (exact, all divisible)
#define NB_HW  916    // 64*29312/8/256
#define NB_CW  2415   // 2240*2208/8/256
#define NB_W1  1104   // 1024*2208/8/256
#define NB_W2  64     // 128*1024/8/256
#define NB_ALL (NB_HW + NB_CW + NB_W1 + NB_W2)

__constant__ int d_LOC[23]  = {0,2490,4912,6895,8797,10612,12320,13913,15364,16748,
                               18086,19437,20770,21914,22984,24004,24907,25740,26544,
                               27130,27774,28241,28749};
// per-head offsets rounded up to 64 (packing layout for head_w bf16 copy)
__constant__ int d_HA64[23] = {0,2496,4928,6912,8832,10688,12416,14016,15488,16896,
                               18240,19648,20992,22144,23232,24256,25216,26112,26944,
                               27584,28288,28800,29312};

__device__ __forceinline__ void g2lds16(const void* g, void* l) {
  __builtin_amdgcn_global_load_lds((const __attribute__((address_space(1))) void*)g,
                                   (__attribute__((address_space(3))) void*)l, 16, 0, 0);
}

__device__ __forceinline__ f32x4 mfma16(bf16x8 a, bf16x8 b, f32x4 c) {
  return __builtin_amdgcn_mfma_f32_16x16x32_bf16(a, b, c, 0, 0, 0);
}

// ---------- fused weight conversion ----------
template<int RR, int CC, int PR, int PC>
__device__ __forceinline__ void cvt_pad8_t(int i, const float* __restrict__ src,
                                           bf16_t* __restrict__ dst)
{
  const int pc8 = PC >> 3;
  int r  = i / pc8;
  int c0 = (i - r * pc8) * 8;
  bf16x8 o;
  if (r < RR && c0 + 8 <= CC) {
    f32x4u a = *(const f32x4u*)(src + (size_t)r * CC + c0);
    f32x4u b = *(const f32x4u*)(src + (size_t)r * CC + c0 + 4);
    #pragma unroll
    for (int j = 0; j < 4; j++) { o[j] = (bf16_t)a[j]; o[4 + j] = (bf16_t)b[j]; }
  } else {
    #pragma unroll
    for (int j = 0; j < 8; j++) {
      int c = c0 + j;
      o[j] = (bf16_t)((r < RR && c < CC) ? src[(size_t)r * CC + c] : 0.0f);
    }
  }
  *(bf16x8*)(dst + (size_t)r * PC + c0) = o;
}

__global__ __launch_bounds__(256) void convert_all(const float* __restrict__ head_w,
                                                   const float* __restrict__ conc_w,
                                                   const float* __restrict__ w1,
                                                   const float* __restrict__ w2,
                                                   bf16_t* __restrict__ headw_ws,
                                                   bf16_t* __restrict__ concw_ws,
                                                   bf16_t* __restrict__ w1_ws,
                                                   bf16_t* __restrict__ w2_ws)
{
  int b = blockIdx.x;
  const int t = threadIdx.x;
  if (b < NB_HW) {
    // head_w repack: (50 x 28749) -> (64 x WH_LD64), per-head 64-aligned, zero pad
    int i  = b * 256 + t;
    const int pc8 = WH_LD64 / 8;
    int r  = i / pc8;
    int c0 = (i - r * pc8) * 8;
    int head = 0;
    #pragma unroll
    for (int h = 0; h < N_HEADS; h++) if (c0 >= d_HA64[h + 1]) head = h + 1;
    const int ha = d_HA64[head], a = d_LOC[head];
    const int L  = d_LOC[head + 1] - a;
    const int k0 = c0 - ha;
    bf16x8 o;
    if (r < 50 && k0 + 8 <= L) {
      const float* s = head_w + (size_t)r * TOTAL_BINS + a + k0;
      f32x4u x = *(const f32x4u*)(s);
      f32x4u y = *(const f32x4u*)(s + 4);
      #pragma unroll
      for (int j = 0; j < 4; j++) { o[j] = (bf16_t)x[j]; o[4 + j] = (bf16_t)y[j]; }
    } else {
      #pragma unroll
      for (int j = 0; j < 8; j++) {
        int k = k0 + j;
        o[j] = (bf16_t)((r < 50 && k < L) ? head_w[(size_t)r * TOTAL_BINS + a + k] : 0.0f);
      }
    }
    *(bf16x8*)(headw_ws + (size_t)r * WH_LD64 + c0) = o;
    return;
  }
  b -= NB_HW;
  if (b < NB_CW) { cvt_pad8_t<IDIM, IDIM, IDIM_NP, IDIM_P>(b * 256 + t, conc_w, concw_ws); return; }
  b -= NB_CW;
  if (b < NB_W1) { cvt_pad8_t<H1DIM, IDIM, H1_NP, IDIM_P>(b * 256 + t, w1, w1_ws); return; }
  b -= NB_W1;
  cvt_pad8_t<H2DIM, H1DIM, 128, H1_NP>(b * 256 + t, w2, w2_ws);
}

// ---------- stage 1: per-head GEMM, A direct-to-reg (prefetched, dwordx4), W LDS dbuf ----------
// grid (ROWS/64, 22); 256 thr = 4 waves; wave owns 16 rows x 64 cols; BK=64; 1 barrier/iter
__global__ __launch_bounds__(256) void head_gemm2(const float* __restrict__ X,
                                                  const bf16_t* __restrict__ Wh,
                                                  const float* __restrict__ headb,
                                                  bf16_t* __restrict__ Cmb)
{
  __shared__ __attribute__((aligned(16))) bf16_t Ws[2][64][72]; // +8 pad: conflict-free phases
  const int tid = threadIdx.x, lane = tid & 63, wid = tid >> 6;
  const int head = blockIdx.y;
  const int a   = d_LOC[head];
  const int ha  = d_HA64[head];
  const int L64 = d_HA64[head + 1] - ha;
  const int m0  = blockIdx.x * 64;
  const int la = lane & 15, lk = lane >> 4;
  const int wrow = m0 + wid * 16 + la;                 // A row this lane feeds
  const uint32_t rowbase = (uint32_t)wrow * TOTAL_BINS + (uint32_t)a;
  const uint32_t MAX4 = (uint32_t)ROWS * TOTAL_BINS - 4;

  // W staging: thread t -> Wh row n=t>>2, 16 bf16 at kgrp=(t&3)*16
  const int sn = tid >> 2, skg = (tid & 3) * 16;
  const bf16_t* wsrc = Wh + (size_t)sn * WH_LD64 + ha + skg;

  f32x4 acc[4] = {};

  // A fragment needs k = kq*32 + lk*8 + j  (two contiguous 32B chunks per lane)
  // tail overrun clamped to MAX4; garbage annihilated by zero-padded W rows.
  #define LOADA(dst, kbase) do {                                     \
    uint32_t b0_ = (kbase) + (uint32_t)(lk * 8);                     \
    dst[0] = *(const f32x4u*)(X + min(b0_,      MAX4));              \
    dst[1] = *(const f32x4u*)(X + min(b0_ + 4,  MAX4));              \
    dst[2] = *(const f32x4u*)(X + min(b0_ + 32, MAX4));              \
    dst[3] = *(const f32x4u*)(X + min(b0_ + 36, MAX4));              \
  } while (0)

  // prolog: W(0) -> Ws[0], prefetch A(0) to regs
  {
    uint4 w0 = *(const uint4*)(wsrc);
    uint4 w1 = *(const uint4*)(wsrc + 8);
    *(uint4*)(&Ws[0][sn][skg])     = w0;
    *(uint4*)(&Ws[0][sn][skg + 8]) = w1;
  }
  f32x4u ar[4];
  LOADA(ar, rowbase);

  const int nIter = L64 >> 6;
  for (int i = 0; i < nIter; i++) {
    __syncthreads();             // Ws[i&1] ready
    const int cur = i & 1, nxt = cur ^ 1;
    uint4 nw0, nw1; f32x4u an[4];
    const bool more = (i + 1 < nIter);
    if (more) {                  // issue next-iter loads early (prefetch)
      const bf16_t* ws2 = wsrc + (size_t)(i + 1) * 64;
      nw0 = *(const uint4*)(ws2);
      nw1 = *(const uint4*)(ws2 + 8);
      LOADA(an, rowbase + (uint32_t)(i + 1) * 64);
    }
    // convert current A to frags: af[kq][j] = X[kb + kq*32 + lk*8 + j]
    bf16x8 af[2];
    #pragma unroll
    for (int kq = 0; kq < 2; kq++)
      #pragma unroll
      for (int j = 0; j < 8; j++)
        af[kq][j] = (bf16_t)ar[kq * 2 + (j >> 2)][j & 3];
    // B frags from LDS + MFMA
    #pragma unroll
    for (int kq = 0; kq < 2; kq++)
      #pragma unroll
      for (int j = 0; j < 4; j++) {
        bf16x8 bf = *(const bf16x8*)(&Ws[cur][j * 16 + la][kq * 32 + lk * 8]);
        acc[j] = mfma16(af[kq], bf, acc[j]);
      }
    if (more) {
      *(uint4*)(&Ws[nxt][sn][skg])     = nw0;
      *(uint4*)(&Ws[nxt][sn][skg + 8]) = nw1;
      #pragma unroll
      for (int q = 0; q < 4; q++) ar[q] = an[q];
    }
  }

  // epilogue: row = b*2+ch -> combined[b, head*100 + ch*50 + o]
  #pragma unroll
  for (int j = 0; j < 4; j++) {
    int o = j * 16 + la;
    if (o < 50) {
      float bv = headb[head * 50 + o];
      #pragma unroll
      for (int r = 0; r < 4; r++) {
        int gr = m0 + wid * 16 + lk * 4 + r;
        Cmb[(size_t)(gr >> 1) * IDIM_P + head * 100 + (gr & 1) * 50 + o] =
            (bf16_t)(acc[j][r] + bv);
      }
    }
  }
  #undef LOADA
}

// ---------- generic bf16 MFMA GEMM, 128x64 tile, dbuf g2lds, XCD-swizzled, optional split-K ----
// C[m,n] = sum_{k in [kb,kb+klen)} A[m,k]*W[n,k] (+bias); wave = 32 rows x 64 cols, BK=32
// f32-out mode writes partials at Cout + z*BATCH*ldc (no bias/act applied upstream of reduce)
__global__ __launch_bounds__(256) void gemm_bt64(const bf16_t* __restrict__ A, int lda,
                                                 const bf16_t* __restrict__ W, int ldb,
                                                 const float* __restrict__ bias,
                                                 void* __restrict__ Cout, int ldc,
                                                 int K, int KCH, int N, int act, int out_f32)
{
  __shared__ __attribute__((aligned(16))) bf16_t As[2][128][32];
  __shared__ __attribute__((aligned(16))) bf16_t Bs[2][64][32];
  const int tid  = threadIdx.x;
  const int lane = tid & 63, wid = tid >> 6;

  // bijective XCD swizzle (nwg % 8 == 0 for all call sites)
  const int gx = gridDim.x;
  int nwg = gx * gridDim.y;
  int l = blockIdx.x + blockIdx.y * gx;
  if ((nwg & 7) == 0) { int q = nwg >> 3; l = (l & 7) * q + (l >> 3); }
  const int m0 = (l % gx) * 128;
  const int n0 = (l / gx) * 64;

  const int kb   = blockIdx.z * KCH;
  const int klen = min(KCH, K - kb);

  const int la = lane & 15, lk = lane >> 4;
  const int wm = wid * 32;
  const int scg = (((tid & 3) ^ ((tid >> 3) & 3)) * 8);   // swizzled source col (elems)
  const int lks = ((lk ^ ((la >> 1) & 3)) * 8);           // swizzled read col (elems)

  f32x4 acc[2][4] = {};

  const bf16_t* asrc0 = A + (size_t)(m0 + (tid >> 2)) * lda + kb + scg;
  const bf16_t* asrc1 = asrc0 + (size_t)64 * lda;
  const bf16_t* wsrc  = W + (size_t)(n0 + (tid >> 2)) * ldb + kb + scg;

  auto stage = [&](int buf, int k0) {
    g2lds16(asrc0 + k0, &As[buf][0][0] + tid * 8);
    g2lds16(asrc1 + k0, &As[buf][64][0] + tid * 8);
    g2lds16(wsrc  + k0, &Bs[buf][0][0] + tid * 8);
  };
  stage(0, 0);

  int i = 0;
  for (int k0 = 0; k0 < klen; k0 += 32, i++) {
    __syncthreads();                       // drains vmcnt -> buf[i&1] ready
    const int cur = i & 1;
    if (k0 + 32 < klen) stage(cur ^ 1, k0 + 32);
    bf16x8 af[2], bfr[4];
    #pragma unroll
    for (int ii = 0; ii < 2; ii++) af[ii]  = *(const bf16x8*)(&As[cur][wm + ii * 16 + la][lks]);
    #pragma unroll
    for (int j = 0; j < 4; j++)    bfr[j] = *(const bf16x8*)(&Bs[cur][j * 16 + la][lks]);
    #pragma unroll
    for (int ii = 0; ii < 2; ii++)
      #pragma unroll
      for (int j = 0; j < 4; j++)
        acc[ii][j] = mfma16(af[ii], bfr[j], acc[ii][j]);
  }

  float bv[4]; bool ok[4]; int gcv[4];
  #pragma unroll
  for (int j = 0; j < 4; j++) {
    int gc = n0 + j * 16 + la;
    gcv[j] = gc; ok[j] = gc < N;
    bv[j] = (bias && ok[j]) ? bias[gc] : 0.0f;
  }
  float* Cf = (float*)Cout + (size_t)blockIdx.z * BATCH * ldc;
  #pragma unroll
  for (int ii = 0; ii < 2; ii++) {
    #pragma unroll
    for (int r = 0; r < 4; r++) {
      int gr = m0 + wm + ii * 16 + lk * 4 + r;
      #pragma unroll
      for (int j = 0; j < 4; j++) {
        if (ok[j]) {
          float v = acc[ii][j][r] + bv[j];
          if (act) v = fmaxf(v, 0.01f * v);
          if (out_f32) Cf[(size_t)gr * ldc + gcv[j]] = v;
          else         ((bf16_t*)Cout)[(size_t)gr * ldc + gcv[j]] = (bf16_t)v;
        }
      }
    }
  }
}

// ---------- w1 split-K reduce: h1 = bf16(lrelu(P0 + P1 + b1)) ----------
// grid 1024; 8 cols/thread over [2048][1024]
__global__ __launch_bounds__(256) void reduce_h1(const float* __restrict__ P,
                                                 const float* __restrict__ bias1,
                                                 bf16_t* __restrict__ h1)
{
  int i  = blockIdx.x * 256 + threadIdx.x;    // 8-packs
  int r  = i >> 7;                            // / (1024/8)
  int c0 = (i & 127) * 8;
  const float* p0 = P + (size_t)r * H1_NP + c0;
  const float* p1 = p0 + (size_t)BATCH * H1_NP;
  f32x4u a0 = *(const f32x4u*)(p0),     a1 = *(const f32x4u*)(p0 + 4);
  f32x4u c0v = *(const f32x4u*)(p1),    c1v = *(const f32x4u*)(p1 + 4);
  float bb[8];
  if (c0 + 8 <= H1DIM) {
    f32x4u x = *(const f32x4u*)(bias1 + c0);
    f32x4u y = *(const f32x4u*)(bias1 + c0 + 4);
    #pragma unroll
    for (int j = 0; j < 4; j++) { bb[j] = x[j]; bb[4 + j] = y[j]; }
  } else {
    #pragma unroll
    for (int j = 0; j < 8; j++) { int c = c0 + j; bb[j] = (c < H1DIM) ? bias1[c] : 0.0f; }
  }
  bf16x8 o;
  #pragma unroll
  for (int j = 0; j < 4; j++) {
    float v = a0[j] + c0v[j] + bb[j];     o[j]     = (bf16_t)fmaxf(v, 0.01f * v);
    float w = a1[j] + c1v[j] + bb[4 + j]; o[4 + j] = (bf16_t)fmaxf(w, 0.01f * w);
  }
  *(bf16x8*)(h1 + (size_t)r * H1_NP + c0) = o;
}

// ---------- stage 4 split-K: P[split][m][n] = sum_{k in chunk} h1[m,k]*w2[n,k] ----------
// grid (16, KSPLIT); 128x64 tile, wave = 32x64, BK=32, dbuf, XCD-swizzled
__global__ __launch_bounds__(256) void gemm_splitk(const bf16_t* __restrict__ A,
                                                   const bf16_t* __restrict__ W,
                                                   float* __restrict__ P)
{
  __shared__ __attribute__((aligned(16))) bf16_t As[2][128][32];
  __shared__ __attribute__((aligned(16))) bf16_t Bs[2][64][32];
  const int tid  = threadIdx.x;
  const int lane = tid & 63, wid = tid >> 6;

  int l = blockIdx.x + blockIdx.y * gridDim.x;    // 128 blocks -> q=16
  { int q = (gridDim.x * gridDim.y) >> 3; l = (l & 7) * q + (l >> 3); }
  const int m0    = (l % gridDim.x) * 128;
  const int split = l / gridDim.x;

  const int kb = split * (H1_NP / KSPLIT);             // 128
  const int la = lane & 15, lk = lane >> 4;
  const int wm = wid * 32;
  const int scg = (((tid & 3) ^ ((tid >> 3) & 3)) * 8);
  const int lks = ((lk ^ ((la >> 1) & 3)) * 8);

  f32x4 acc[2][4] = {};

  const bf16_t* asrc0 = A + (size_t)(m0 + (tid >> 2)) * H1_NP + kb + scg;
  const bf16_t* asrc1 = asrc0 + (size_t)64 * H1_NP;
  const bf16_t* wsrc  = W + (size_t)(tid >> 2) * H1_NP + kb + scg;

  auto stage = [&](int buf, int k0) {
    g2lds16(asrc0 + k0, &As[buf][0][0] + tid * 8);
    g2lds16(asrc1 + k0, &As[buf][64][0] + tid * 8);
    g2lds16(wsrc  + k0, &Bs[buf][0][0] + tid * 8);
  };
  stage(0, 0);

  #pragma unroll
  for (int i = 0; i < 4; i++) {                        // 4 * BK32 = 128
    __syncthreads();
    const int cur = i & 1;
    if (i < 3) stage(cur ^ 1, (i + 1) * 32);
    bf16x8 af[2], bfr[4];
    #pragma unroll
    for (int ii = 0; ii < 2; ii++) af[ii]  = *(const bf16x8*)(&As[cur][wm + ii * 16 + la][lks]);
    #pragma unroll
    for (int j = 0; j < 4; j++)    bfr[j] = *(const bf16x8*)(&Bs[cur][j * 16 + la][lks]);
    #pragma unroll
    for (int ii = 0; ii < 2; ii++)
      #pragma unroll
      for (int j = 0; j < 4; j++)
        acc[ii][j] = mfma16(af[ii], bfr[j], acc[ii][j]);
  }

  #pragma unroll
  for (int ii = 0; ii < 2; ii++)
    #pragma unroll
    for (int r = 0; r < 4; r++) {
      int gr = m0 + wm + ii * 16 + lk * 4 + r;
      #pragma unroll
      for (int j = 0; j < 4; j++)
        P[((size_t)split * BATCH + gr) * 64 + j * 16 + la] = acc[ii][j][r];
    }
}

// ---------- stage 5: sum splits + bias + lrelu, then 13-wide output GEMM (VALU) ----------
// grid (BATCH/16); block 256
__global__ __launch_bounds__(256) void finalize_tail(const float* __restrict__ P,
                                                     const float* __restrict__ b2,
                                                     const float* __restrict__ w3,
                                                     const float* __restrict__ b3,
                                                     float* __restrict__ out)
{
  __shared__ float h2s[16][64];
  const int r0 = blockIdx.x * 16;
  const int t = threadIdx.x;
  const int r = t >> 4, c4 = (t & 15) * 4;
  f32x4 s = {};
  #pragma unroll
  for (int sp = 0; sp < KSPLIT; sp++) {
    const f32x4 v = *(const f32x4*)(P + ((size_t)sp * BATCH + r0 + r) * 64 + c4);
    s.x += v.x; s.y += v.y; s.z += v.z; s.w += v.w;
  }
  #pragma unroll
  for (int c = 0; c < 4; c++) {
    int col = c4 + c;
    float v = s[c] + ((col < H2DIM) ? b2[col] : 0.0f);
    h2s[r][col] = fmaxf(v, 0.01f * v);
  }
  __syncthreads();
  if (t < 16 * ODIM) {
    int rr = t / ODIM, o = t - rr * ODIM;
    float acc = b3[o];
    #pragma unroll 10
    for (int k = 0; k < H2DIM; k++) acc += h2s[rr][k] * w3[o * H2DIM + k];
    out[(size_t)(r0 + rr) * ODIM + o] = acc;
  }
}

extern "C" void kernel_launch(void* const* d_in, const int* in_sizes, int n_in,
                              void* d_out, int out_size, void* d_ws, size_t ws_size,
                              hipStream_t stream)
{
  const float* X      = (const float*)d_in[0];
  const float* head_w = (const float*)d_in[1];
  const float* head_b = (const float*)d_in[2];
  const float* conc_w = (const float*)d_in[3];
  const float* conc_b = (const float*)d_in[4];
  const float* w1     = (const float*)d_in[5];
  const float* b1     = (const float*)d_in[6];
  const float* w2     = (const float*)d_in[7];
  const float* b2     = (const float*)d_in[8];
  const float* w3     = (const float*)d_in[9];
  const float* b3     = (const float*)d_in[10];

  char* p = (char*)d_ws;
  auto alloc = [&](size_t bytes) { char* r = p; p += (bytes + 255) & ~(size_t)255; return r; };
  bf16_t* headw_ws = (bf16_t*)alloc((size_t)64 * WH_LD64 * 2);     // 3.75 MB
  bf16_t* concw_ws = (bf16_t*)alloc((size_t)IDIM_NP * IDIM_P * 2); // 9.9 MB
  bf16_t* w1_ws    = (bf16_t*)alloc((size_t)H1_NP * IDIM_P * 2);   // 4.5 MB
  bf16_t* w2_ws    = (bf16_t*)alloc((size_t)128 * H1_NP * 2);      // 0.26 MB
  bf16_t* comb     = (bf16_t*)alloc((size_t)BATCH * IDIM_P * 2);   // 9.0 MB
  bf16_t* zbuf     = (bf16_t*)alloc((size_t)BATCH * IDIM_P * 2);   // 9.0 MB
  bf16_t* h1buf    = (bf16_t*)alloc((size_t)BATCH * H1_NP * 2);    // 4.2 MB
  float*  h2p      = (float*) alloc((size_t)KSPLIT * BATCH * 64 * 4); // 4.0 MB
  float*  h1p      = (float*) alloc((size_t)2 * BATCH * H1_NP * 4);   // 16.8 MB

  convert_all<<<dim3(NB_ALL), 256, 0, stream>>>(head_w, conc_w, w1, w2,
                                                headw_ws, concw_ws, w1_ws, w2_ws);

  head_gemm2<<<dim3(ROWS / 64, N_HEADS), 256, 0, stream>>>(X, headw_ws, head_b, comb);

  // conc: single chunk (z=1), bf16 out with bias
  gemm_bt64<<<dim3(BATCH / 128, IDIM_NP / 64, 1), 256, 0, stream>>>(
      comb, IDIM_P, concw_ws, IDIM_P, conc_b, zbuf, IDIM_P, IDIM_P, IDIM_P, IDIM, 0, 0);

  // w1: split-K=2 (1120+1088), f32 partials, no bias/act (applied in reduce)
  gemm_bt64<<<dim3(BATCH / 128, H1_NP / 64, 2), 256, 0, stream>>>(
      zbuf, IDIM_P, w1_ws, IDIM_P, nullptr, h1p, H1_NP, IDIM_P, KCH_W1, H1_NP, 0, 1);

  reduce_h1<<<dim3(BATCH * H1_NP / 8 / 256), 256, 0, stream>>>(h1p, b1, h1buf);

  gemm_splitk<<<dim3(BATCH / 128, KSPLIT), 256, 0, stream>>>(h1buf, w2_ws, h2p);
  finalize_tail<<<dim3(BATCH / 16), 256, 0, stream>>>(h2p, b2, w3, b3, (float*)d_out);
}